// Round 11
// baseline (385.406 us; speedup 1.0000x reference)
//
#include <hip/hip_runtime.h>
#include <cstdint>
#include <cstddef>

#define D_MODEL 2048
#define SEQ     2048
#define NB      2
#define ROWS    4096      // NB*SEQ
#define QKV_N   3072      // 2048 + 2*4*128
#define NH      16
#define NKV     4
#define HD      128
#define EPSV    1e-5f
// 1/sqrt(128) * log2(e): folded into Q at RoPE time -> scores arrive in log2 domain
#define QPRE    (0.08838834764831845f * 1.4426950408889634f)

typedef unsigned short ushort_t;
typedef __attribute__((ext_vector_type(8)))  short short8;
typedef __attribute__((ext_vector_type(4)))  float floatx4;
typedef __attribute__((ext_vector_type(16))) float floatx16;

__device__ __forceinline__ ushort_t f2b(float f) {
    unsigned u = __float_as_uint(f);
    u += 0x7fffu + ((u >> 16) & 1u);   // RNE bf16
    return (ushort_t)(u >> 16);
}
__device__ __forceinline__ float b2f(ushort_t u) {
    return __uint_as_float(((unsigned)u) << 16);
}

// pack two f32 -> bf16 pair (lo in low 16 bits)
__device__ __forceinline__ unsigned pkbf(float lo, float hi) {
    unsigned u0 = __float_as_uint(lo) + 0x8000u;
    unsigned u1 = __float_as_uint(hi) + 0x8000u;
    return __builtin_amdgcn_perm(u1, u0, 0x07060302u);
}

// exchange register halves across the lane<32 / lane>=32 boundary:
//   x[i<32]=a[i], x[i>=32]=b[i-32];  y[i<32]=a[i+32], y[i>=32]=b[i]
// (permlane32_swap semantics, built from proven shfl_xor primitives)
__device__ __forceinline__ void swap2(unsigned a, unsigned b, int hi,
                                      unsigned &x, unsigned &y) {
    unsigned ta = __shfl_xor(a, 32);
    unsigned tb = __shfl_xor(b, 32);
    x = hi ? tb : a;
    y = hi ? b : ta;
}

#define GLD_LDS16(gp, lp) __builtin_amdgcn_global_load_lds( \
    (const __attribute__((address_space(1))) void*)(gp),   \
    (__attribute__((address_space(3))) void*)(lp), 16, 0, 0)

// ---------------- RMSNorm (fp32 in) -> bf16 out -----------------------------
__global__ __launch_bounds__(256) void k_rmsnorm_bf16(
        const float* __restrict__ x, const float* __restrict__ w,
        ushort_t* __restrict__ out) {
    int row = blockIdx.x, t = threadIdx.x;
    const float4* xr = (const float4*)(x + (size_t)row * D_MODEL);
    float4 a = xr[t], b = xr[t + 256];
    float ss = a.x*a.x + a.y*a.y + a.z*a.z + a.w*a.w
             + b.x*b.x + b.y*b.y + b.z*b.z + b.w*b.w;
    for (int m = 1; m < 64; m <<= 1) ss += __shfl_xor(ss, m);
    __shared__ float sred[4];
    if ((t & 63) == 0) sred[t >> 6] = ss;
    __syncthreads();
    float r = rsqrtf((sred[0] + sred[1] + sred[2] + sred[3]) * (1.0f / D_MODEL) + EPSV);
    const float4* wr = (const float4*)w;
    float4 wa = wr[t], wb = wr[t + 256];
    ushort4 pa, pb;
    pa.x = f2b(a.x * r * wa.x); pa.y = f2b(a.y * r * wa.y);
    pa.z = f2b(a.z * r * wa.z); pa.w = f2b(a.w * r * wa.w);
    pb.x = f2b(b.x * r * wb.x); pb.y = f2b(b.y * r * wb.y);
    pb.z = f2b(b.z * r * wb.z); pb.w = f2b(b.w * r * wb.w);
    ushort4* o = (ushort4*)(out + (size_t)row * D_MODEL);
    o[t] = pa; o[t + 256] = pb;
}

// ---------------- RMSNorm (fp32 in) -> fp32 out -----------------------------
__global__ __launch_bounds__(256) void k_rmsnorm_f32(
        const float* __restrict__ x, const float* __restrict__ w,
        float* __restrict__ out) {
    int row = blockIdx.x, t = threadIdx.x;
    const float4* xr = (const float4*)(x + (size_t)row * D_MODEL);
    float4 a = xr[t], b = xr[t + 256];
    float ss = a.x*a.x + a.y*a.y + a.z*a.z + a.w*a.w
             + b.x*b.x + b.y*b.y + b.z*b.z + b.w*b.w;
    for (int m = 1; m < 64; m <<= 1) ss += __shfl_xor(ss, m);
    __shared__ float sred[4];
    if ((t & 63) == 0) sred[t >> 6] = ss;
    __syncthreads();
    float r = rsqrtf((sred[0] + sred[1] + sred[2] + sred[3]) * (1.0f / D_MODEL) + EPSV);
    const float4* wr = (const float4*)w;
    float4 wa = wr[t], wb = wr[t + 256];
    float4 oa, ob;
    oa.x = a.x * r * wa.x; oa.y = a.y * r * wa.y; oa.z = a.z * r * wa.z; oa.w = a.w * r * wa.w;
    ob.x = b.x * r * wb.x; ob.y = b.y * r * wb.y; ob.z = b.z * r * wb.z; ob.w = b.w * r * wb.w;
    float4* o = (float4*)(out + (size_t)row * D_MODEL);
    o[t] = oa; o[t + 256] = ob;
}

// -------- transpose + fp32->bf16: in [R][C] -> out [C][R] -------------------
__global__ __launch_bounds__(256) void k_transpose_cvt(
        const float* __restrict__ in, ushort_t* __restrict__ out, int R, int C) {
    __shared__ float tile[32][33];
    int bc = blockIdx.x * 32, br = blockIdx.y * 32;
    int t = threadIdx.x, lr = t >> 5, lc = t & 31;
    for (int i = 0; i < 4; i++)
        tile[lr + i * 8][lc] = in[(size_t)(br + lr + i * 8) * C + bc + lc];
    __syncthreads();
    for (int i = 0; i < 4; i++)
        out[(size_t)(bc + lr + i * 8) * R + br + lc] = f2b(tile[lc][lr + i * 8]);
}

// -------- GEMM v2 (m97 structure, BK=64): C = A[M,K](bf16)*Bt[N,K](bf16) ----
// R10-proven (-13us vs BK=32). XOR-swizzle via pre-swizzled global source.
template <int MODE>
__global__ __launch_bounds__(256) void k_gemm(
        const ushort_t* __restrict__ A, const ushort_t* __restrict__ Bt,
        void* __restrict__ Cout, const float* __restrict__ resid,
        int M, int N, int K) {
    __shared__ __align__(16) ushort_t sA[128 * 64];
    __shared__ __align__(16) ushort_t sB[128 * 64];
    int bm = blockIdx.y * 128, bn = blockIdx.x * 128;
    int t = threadIdx.x;
    int wv = t >> 6, lane = t & 63;
    int wm = (wv >> 1) * 64, wn = (wv & 1) * 64;
    int q4 = lane >> 4, n16 = lane & 15;

    int srow8 = lane >> 3;                     // 0..7
    int sxor  = ((lane & 7) ^ srow8) * 8;      // swizzled 16B-chunk offset
    const ushort_t* gA = A  + (size_t)(bm + wv * 32 + srow8) * K + sxor;
    const ushort_t* gB = Bt + (size_t)(bn + wv * 32 + srow8) * K + sxor;
    ushort_t* lA = sA + wv * 32 * 64;
    ushort_t* lB = sB + wv * 32 * 64;

    floatx4 zero4 = {0.0f, 0.0f, 0.0f, 0.0f};
    floatx4 acc[4][4];
    for (int i = 0; i < 4; i++)
        for (int j = 0; j < 4; j++) acc[i][j] = zero4;

    for (int k0 = 0; k0 < K; k0 += 64) {
        #pragma unroll
        for (int i = 0; i < 4; i++) {
            GLD_LDS16(gA + (size_t)(i * 8) * K + k0, lA + i * 8 * 64);
            GLD_LDS16(gB + (size_t)(i * 8) * K + k0, lB + i * 8 * 64);
        }
        __syncthreads();
        #pragma unroll
        for (int kk = 0; kk < 2; kk++) {
            short8 af[4], bfr[4];
            for (int i = 0; i < 4; i++) {
                int row = wm + i * 16 + n16;
                af[i]  = *(const short8*)&sA[row * 64 + (((kk * 4 + q4) ^ (row & 7)) * 8)];
            }
            for (int j = 0; j < 4; j++) {
                int row = wn + j * 16 + n16;
                bfr[j] = *(const short8*)&sB[row * 64 + (((kk * 4 + q4) ^ (row & 7)) * 8)];
            }
            for (int i = 0; i < 4; i++)
                for (int j = 0; j < 4; j++)
                    acc[i][j] = __builtin_amdgcn_mfma_f32_16x16x32_bf16(af[i], bfr[j], acc[i][j], 0, 0, 0);
        }
        __syncthreads();
    }

    for (int i = 0; i < 4; i++) {
        int rbase = bm + wm + i * 16 + q4 * 4;
        for (int j = 0; j < 4; j++) {
            int col = bn + wn + j * 16 + n16;
            if (MODE == 0) {
                ushort_t* C = (ushort_t*)Cout;
                for (int r = 0; r < 4; r++) {
                    float v = acc[i][j][r];
                    v = fminf(fmaxf(v, -8.0f), 8.0f);
                    C[(size_t)(rbase + r) * N + col] = f2b(v);
                }
            } else {
                float* C = (float*)Cout;
                for (int r = 0; r < 4; r++) {
                    float v = acc[i][j][r] + resid[(size_t)(rbase + r) * N + col];
                    C[(size_t)(rbase + r) * N + col] = v;
                }
            }
        }
    }
}

// -------- RoPE + scatter; Q pre-scaled by 1/sqrt(d)*log2e -------------------
__global__ __launch_bounds__(256) void k_rope(
        const ushort_t* __restrict__ qkv, const int* __restrict__ pos_ids,
        const float* __restrict__ rsin, const float* __restrict__ rcos,
        ushort_t* __restrict__ qout, ushort_t* __restrict__ kout) {
    int wid  = blockIdx.x * 4 + (threadIdx.x >> 6);
    int lane = threadIdx.x & 63;
    int row = wid / 20, slot = wid - row * 20;
    int b = row >> 11, s = row & 2047;
    int pos = pos_ids[row];
    int col0 = (slot < 16) ? slot * HD : D_MODEL + (slot - 16) * HD;
    const ushort_t* src = qkv + (size_t)row * QKV_N + col0;
    float xl = b2f(src[lane]);
    float xh = b2f(src[lane + 64]);
    const float* cp = rcos + (size_t)pos * HD;
    const float* sp = rsin + (size_t)pos * HD;
    float cl = cp[lane], sl = sp[lane];
    float ch = cp[lane + 64], sh = sp[lane + 64];
    float mul = (slot < 16) ? QPRE : 1.0f;
    float ol = (xl * cl - xh * sl) * mul;
    float oh = (xh * ch + xl * sh) * mul;
    if (slot < 16) {
        size_t dst = ((size_t)(b * NH + slot) * SEQ + s) * HD;
        qout[dst + lane] = f2b(ol); qout[dst + lane + 64] = f2b(oh);
    } else {
        size_t dst = ((size_t)(b * NKV + (slot - 16)) * SEQ + s) * HD;
        kout[dst + lane] = f2b(ol); kout[dst + lane + 64] = f2b(oh);
    }
}

// -------- V transpose: qkv v-slot -> vt [NB,NKV,HD,SEQ] ---------------------
__global__ __launch_bounds__(256) void k_vtrans(
        const ushort_t* __restrict__ qkv, ushort_t* __restrict__ vt) {
    __shared__ ushort_t tile[32][33];
    int bh = blockIdx.z;
    int b = bh >> 2, h = bh & 3;
    int s0 = blockIdx.x * 32, d0 = blockIdx.y * 32;
    int t = threadIdx.x, lr = t >> 5, lc = t & 31;
    int col0 = D_MODEL + NKV * HD + h * HD;
    for (int i = 0; i < 4; i++)
        tile[lr + i * 8][lc] =
            qkv[((size_t)b * SEQ + s0 + lr + i * 8) * QKV_N + col0 + d0 + lc];
    __syncthreads();
    for (int i = 0; i < 4; i++)
        vt[((size_t)bh * HD + d0 + lr + i * 8) * SEQ + s0 + lc] = tile[lc][lr + i * 8];
}

// -------- MFMA flash attention v9: 32x32 MFMA, 32q/wave, diagonal pairing ---
// Rationale: v5 family frozen at ~102us = LDS-BW bound at 8 FLOP/byte
// (16x16x32 frags). 32x32x16 frags deliver 32 FLOP/byte -> per-q LDS traffic
// and per-q softmax VALU halve. Block = 4 waves x 32 q = 128 q, split as
// diagonal tile pair (p, 31-p): waves 0,1 -> q-tile p; waves 2,3 -> 31-p.
// Every block = exactly 66 compute-wave-iters -> perfect balance; 512 blocks
// = 2/CU (64KB LDS dbuf), all resident. Staging + swizzles verbatim from v5.
// Layout safety: QK^T and PV are immune to A/B k-slot-order assumptions
// (same mapping used for both operands -> dot invariant under permutation);
// the only exact requirement is the HW-verified 32x32 C/D map
// (col=lane&31, row=(reg&3)+8*(reg>>2)+4*(lane>>5)), used for mask/softmax/
// P^T assembly (via lane^32 swap2) and the O epilogue.
__global__ __launch_bounds__(256, 2) void k_attn(
        const ushort_t* __restrict__ Q, const ushort_t* __restrict__ Kr,
        const ushort_t* __restrict__ Vt, const int* __restrict__ amask,
        ushort_t* __restrict__ O) {
    int bidx = blockIdx.x;
    int p = bidx >> 5;                        // 0..15; p=0 (longest staging) first
    int bh = bidx & 31, h = bh & 15, b = bh >> 4;
    int wave = threadIdx.x >> 6, lane = threadIdx.x & 63;
    int q32 = lane & 31, hi = lane >> 5;

    __shared__ __align__(16) ushort_t sK[2][64 * 128];   // [kv][d], chunk-swizzled
    __shared__ __align__(16) ushort_t sV[2][128 * 64];   // [d][kv], chunk-swizzled

    const ushort_t* Qh = Q  + (size_t)bh * SEQ * HD;
    const ushort_t* Kh = Kr + (size_t)(b * NKV + (h >> 2)) * SEQ * HD;
    const ushort_t* Vh = Vt + (size_t)(b * NKV + (h >> 2)) * HD * SEQ;
    const int* am = amask + b * SEQ;

    int ph = 31 - p;
    int qb = (wave < 2) ? (p * 64 + wave * 32) : (ph * 64 + (wave - 2) * 32);
    int qcol = qb + q32;                       // this lane's q column

    // Q as B-frag for 32x32x16: n = q32, k(d) = kk*16 + hi*8 + j
    short8 qf[8];
    #pragma unroll
    for (int kk = 0; kk < 8; kk++)
        qf[kk] = *(const short8*)(Qh + (size_t)qcol * HD + kk * 16 + hi * 8);

    const floatx16 zero16 = {0,0,0,0, 0,0,0,0, 0,0,0,0, 0,0,0,0};
    floatx16 o_acc[4];                         // O^T[d][q]: d = dt*32 + (r&3)+8*(r>>2)+4*hi
    #pragma unroll
    for (int dt = 0; dt < 4; dt++) o_acc[dt] = zero16;
    float m_i = -INFINITY, l_i = 0.0f;

    // staging lane geometry (verbatim v5)
    int krow_l = (lane >> 4);                  // + wave*16 + t*4
    int kc_l   = lane & 15;
    int vrow_l = (lane >> 3);                  // + wave*32 + t*8
    int vc_l   = lane & 7;

    auto stage_kv = [&](int buf, int kv0) {
        #pragma unroll
        for (int t = 0; t < 4; t++) {
            int krow = wave * 16 + t * 4 + krow_l;
            int kc   = kc_l ^ (krow & 7);
            GLD_LDS16(Kh + (size_t)(kv0 + krow) * HD + kc * 8,
                      &sK[buf][(wave * 16 + t * 4) * 128]);
            int vrow = wave * 32 + t * 8 + vrow_l;
            int vc   = vc_l ^ (vrow & 7);
            GLD_LDS16(Vh + (size_t)vrow * SEQ + kv0 + vc * 8,
                      &sV[buf][(wave * 32 + t * 8) * 64]);
        }
    };

    int kv_iters = 32 - p;                     // high tile's causal range

    stage_kv(0, 0);
    asm volatile("s_waitcnt vmcnt(0)" ::: "memory");
    __builtin_amdgcn_s_barrier();
    __builtin_amdgcn_sched_barrier(0);

    for (int it = 0; it < kv_iters; it++) {
        int cur = it & 1;
        int kv0 = it * 64;
        if (it + 1 < kv_iters)
            stage_kv(cur ^ 1, kv0 + 64);

        const ushort_t* sKc = sK[cur];
        const ushort_t* sVc = sV[cur];

        if (kv0 <= qb + 31) {                  // wave-uniform active predicate
            bool tail = (kv0 + 63 > qb);
            // ---- S^T = K·Q^T, two 32-kv halves of 32x32 MFMA ----
            floatx16 st[2];
            st[0] = zero16; st[1] = zero16;
            #pragma unroll
            for (int half = 0; half < 2; half++) {
                int krow = half * 32 + q32;    // A rows m = kv
                int sw = krow & 7;
                const ushort_t* kb = sKc + krow * 128;
                #pragma unroll
                for (int kk = 0; kk < 8; kk++) {
                    short8 kf = *(const short8*)(kb + (((2 * kk + hi) ^ sw) * 8));
                    st[half] = __builtin_amdgcn_mfma_f32_32x32x16_bf16(kf, qf[kk], st[half], 0, 0, 0);
                }
            }
            // ---- mask: reg r of half -> kv = kv0+half*32+8*(r>>2)+4*hi+(r&3) ----
            #pragma unroll
            for (int half = 0; half < 2; half++) {
                #pragma unroll
                for (int g = 0; g < 4; g++) {
                    int kvb = kv0 + half * 32 + 8 * g + 4 * hi;
                    int4 am4 = *(const int4*)(am + kvb);
                    int amr[4] = {am4.x, am4.y, am4.z, am4.w};
                    #pragma unroll
                    for (int r2 = 0; r2 < 4; r2++) {
                        bool ok = (amr[r2] > 0) && (!tail || (kvb + r2 <= qcol));
                        st[half][g * 4 + r2] = ok ? st[half][g * 4 + r2] : -1e30f;
                    }
                }
            }
            // ---- online softmax: per-lane 32 values, ONE lane^32 exchange ----
            float mx = -INFINITY;
            #pragma unroll
            for (int half = 0; half < 2; half++)
                #pragma unroll
                for (int r = 0; r < 16; r++) mx = fmaxf(mx, st[half][r]);
            mx = fmaxf(mx, __shfl_xor(mx, 32));
            if (!__all(mx - m_i <= 8.0f)) {    // T13 deferred rescale (log2 dom)
                float mnew = fmaxf(m_i, mx);
                float al = exp2f(m_i - mnew);
                m_i = mnew;
                l_i *= al;
                #pragma unroll
                for (int dt = 0; dt < 4; dt++) o_acc[dt] *= al;
            }
            float rs = 0.0f;
            #pragma unroll
            for (int half = 0; half < 2; half++)
                #pragma unroll
                for (int r = 0; r < 16; r++) {
                    float pv = exp2f(st[half][r] - m_i);
                    st[half][r] = pv;
                    rs += pv;
                }
            rs += __shfl_xor(rs, 32);
            l_i += rs;
            // ---- PV: B = P^T frags via pkbf + swap2; A = V^T from LDS ----
            #pragma unroll
            for (int half = 0; half < 2; half++) {
                unsigned pk01 = pkbf(st[half][0],  st[half][1]);
                unsigned pk23 = pkbf(st[half][2],  st[half][3]);
                unsigned pk45 = pkbf(st[half][4],  st[half][5]);
                unsigned pk67 = pkbf(st[half][6],  st[half][7]);
                unsigned pk89 = pkbf(st[half][8],  st[half][9]);
                unsigned pkab = pkbf(st[half][10], st[half][11]);
                unsigned pkcd = pkbf(st[half][12], st[half][13]);
                unsigned pkef = pkbf(st[half][14], st[half][15]);
                unsigned w0, w1, w2, w3;
                union { unsigned u[4]; short8 s; } f0, f1;
                swap2(pk01, pk45, hi, w0, w2);
                swap2(pk23, pk67, hi, w1, w3);
                f0.u[0] = w0; f0.u[1] = w1; f0.u[2] = w2; f0.u[3] = w3;
                swap2(pk89, pkcd, hi, w0, w2);
                swap2(pkab, pkef, hi, w1, w3);
                f1.u[0] = w0; f1.u[1] = w1; f1.u[2] = w2; f1.u[3] = w3;
                #pragma unroll
                for (int ks = 0; ks < 2; ks++) {
                    short8 pf = ks ? f1.s : f0.s;
                    int cg = (half * 2 + ks) * 2 + hi;   // global 16B kv-chunk
                    #pragma unroll
                    for (int dt = 0; dt < 4; dt++) {
                        int vrow = dt * 32 + q32;
                        short8 vf = *(const short8*)(sVc + vrow * 64 + ((cg ^ (vrow & 7)) * 8));
                        o_acc[dt] = __builtin_amdgcn_mfma_f32_32x32x16_bf16(vf, pf, o_acc[dt], 0, 0, 0);
                    }
                }
            }
        }
        // ---- single per-iter drain (v5-proven pipeline) ----
        asm volatile("s_waitcnt vmcnt(0)" ::: "memory");
        __builtin_amdgcn_s_barrier();
        __builtin_amdgcn_sched_barrier(0);
    }
    // ---- epilogue: lane holds q=q32; reg r of dt -> d = dt*32+8*(r>>2)+4*hi+(r&3)
    float inv = 1.0f / l_i;
    ushort_t* orow = O + ((size_t)(b * SEQ) + qcol) * D_MODEL + h * HD;
    #pragma unroll
    for (int dt = 0; dt < 4; dt++)
        #pragma unroll
        for (int g = 0; g < 4; g++) {
            uint2 pk;
            pk.x = pkbf(o_acc[dt][4 * g]     * inv, o_acc[dt][4 * g + 1] * inv);
            pk.y = pkbf(o_acc[dt][4 * g + 2] * inv, o_acc[dt][4 * g + 3] * inv);
            *(uint2*)(orow + dt * 32 + 8 * g + 4 * hi) = pk;
        }
}

// ---------------------------------------------------------------------------
extern "C" void kernel_launch(void* const* d_in, const int* in_sizes, int n_in,
                              void* d_out, int out_size, void* d_ws, size_t ws_size,
                              hipStream_t stream) {
    const float* hidden = (const float*)d_in[0];
    const int*   amask  = (const int*)d_in[1];
    const int*   pos    = (const int*)d_in[2];
    const float* wqkv   = (const float*)d_in[3];
    const float* wout   = (const float*)d_in[4];
    const float* n1w    = (const float*)d_in[5];
    const float* n2w    = (const float*)d_in[6];
    const float* rsin   = (const float*)d_in[7];
    const float* rcos   = (const float*)d_in[8];
    float* out0 = (float*)d_out;
    float* out1 = out0 + (size_t)ROWS * D_MODEL;

    char* ws = (char*)d_ws;
    ushort_t* x_bf    = (ushort_t*)ws;  ws += (size_t)ROWS * D_MODEL * 2;
    ushort_t* wqkv_t  = (ushort_t*)ws;  ws += (size_t)QKV_N * D_MODEL * 2;
    ushort_t* wout_t  = (ushort_t*)ws;  ws += (size_t)D_MODEL * D_MODEL * 2;
    ushort_t* qkv     = (ushort_t*)ws;  ws += (size_t)ROWS * QKV_N * 2;
    ushort_t* qrot    = (ushort_t*)ws;  ws += (size_t)NB * NH * SEQ * HD * 2;
    ushort_t* krot    = (ushort_t*)ws;  ws += (size_t)NB * NKV * SEQ * HD * 2;
    ushort_t* vt      = (ushort_t*)ws;  ws += (size_t)NB * NKV * HD * SEQ * 2;
    ushort_t* attn    = (ushort_t*)ws;  ws += (size_t)ROWS * D_MODEL * 2;

    k_rmsnorm_bf16<<<ROWS, 256, 0, stream>>>(hidden, n1w, x_bf);
    k_transpose_cvt<<<dim3(QKV_N / 32, D_MODEL / 32), 256, 0, stream>>>(wqkv, wqkv_t, D_MODEL, QKV_N);
    k_transpose_cvt<<<dim3(D_MODEL / 32, D_MODEL / 32), 256, 0, stream>>>(wout, wout_t, D_MODEL, D_MODEL);
    k_gemm<0><<<dim3(QKV_N / 128, ROWS / 128), 256, 0, stream>>>(x_bf, wqkv_t, qkv, nullptr, ROWS, QKV_N, D_MODEL);
    k_rope<<<ROWS * 20 / 4, 256, 0, stream>>>(qkv, pos, rsin, rcos, qrot, krot);
    k_vtrans<<<dim3(SEQ / 32, HD / 32, NB * NKV), 256, 0, stream>>>(qkv, vt);
    k_attn<<<16 * 32, 256, 0, stream>>>(qrot, krot, vt, amask, attn);
    k_gemm<1><<<dim3(D_MODEL / 128, ROWS / 128), 256, 0, stream>>>(attn, wout_t, out0, hidden, ROWS, D_MODEL, D_MODEL);
    k_rmsnorm_f32<<<ROWS, 256, 0, stream>>>(out0, n2w, out1);
}

// Round 12
// 376.710 us; speedup vs baseline: 1.0231x; 1.0231x over previous
//
#include <hip/hip_runtime.h>
#include <cstdint>
#include <cstddef>

#define D_MODEL 2048
#define SEQ     2048
#define NB      2
#define ROWS    4096      // NB*SEQ
#define QKV_N   3072      // 2048 + 2*4*128
#define NH      16
#define NKV     4
#define HD      128
#define EPSV    1e-5f
// 1/sqrt(128) * log2(e): folded into Q at RoPE time -> scores arrive in log2 domain
#define QPRE    (0.08838834764831845f * 1.4426950408889634f)

typedef unsigned short ushort_t;
typedef __attribute__((ext_vector_type(8))) short  short8;
typedef __attribute__((ext_vector_type(4))) short  short4v;
typedef __attribute__((ext_vector_type(4))) float  floatx4;

__device__ __forceinline__ ushort_t f2b(float f) {
    unsigned u = __float_as_uint(f);
    u += 0x7fffu + ((u >> 16) & 1u);   // RNE bf16
    return (ushort_t)(u >> 16);
}
__device__ __forceinline__ float b2f(ushort_t u) {
    return __uint_as_float(((unsigned)u) << 16);
}

// pack two f32 -> bf16 pair
__device__ __forceinline__ unsigned pkbf(float lo, float hi) {
    unsigned u0 = __float_as_uint(lo) + 0x8000u;
    unsigned u1 = __float_as_uint(hi) + 0x8000u;
    return __builtin_amdgcn_perm(u1, u0, 0x07060302u);
}

#if __has_builtin(__builtin_amdgcn_mfma_f32_16x16x16bf16_1k)
#define HAVE_1K 1
#endif

__device__ __forceinline__ floatx4 pv_mfma(short4v a, short4v b, floatx4 c) {
#ifdef HAVE_1K
    return __builtin_amdgcn_mfma_f32_16x16x16bf16_1k(a, b, c, 0, 0, 0);
#else
    short8 a8 = {a[0], a[1], a[2], a[3], 0, 0, 0, 0};
    short8 b8 = {b[0], b[1], b[2], b[3], 0, 0, 0, 0};
    return __builtin_amdgcn_mfma_f32_16x16x32_bf16(a8, b8, c, 0, 0, 0);
#endif
}

#define GLD_LDS16(gp, lp) __builtin_amdgcn_global_load_lds( \
    (const __attribute__((address_space(1))) void*)(gp),   \
    (__attribute__((address_space(3))) void*)(lp), 16, 0, 0)

// ---------------- RMSNorm (fp32 in) -> bf16 out -----------------------------
__global__ __launch_bounds__(256) void k_rmsnorm_bf16(
        const float* __restrict__ x, const float* __restrict__ w,
        ushort_t* __restrict__ out) {
    int row = blockIdx.x, t = threadIdx.x;
    const float4* xr = (const float4*)(x + (size_t)row * D_MODEL);
    float4 a = xr[t], b = xr[t + 256];
    float ss = a.x*a.x + a.y*a.y + a.z*a.z + a.w*a.w
             + b.x*b.x + b.y*b.y + b.z*b.z + b.w*b.w;
    for (int m = 1; m < 64; m <<= 1) ss += __shfl_xor(ss, m);
    __shared__ float sred[4];
    if ((t & 63) == 0) sred[t >> 6] = ss;
    __syncthreads();
    float r = rsqrtf((sred[0] + sred[1] + sred[2] + sred[3]) * (1.0f / D_MODEL) + EPSV);
    const float4* wr = (const float4*)w;
    float4 wa = wr[t], wb = wr[t + 256];
    ushort4 pa, pb;
    pa.x = f2b(a.x * r * wa.x); pa.y = f2b(a.y * r * wa.y);
    pa.z = f2b(a.z * r * wa.z); pa.w = f2b(a.w * r * wa.w);
    pb.x = f2b(b.x * r * wb.x); pb.y = f2b(b.y * r * wb.y);
    pb.z = f2b(b.z * r * wb.z); pb.w = f2b(b.w * r * wb.w);
    ushort4* o = (ushort4*)(out + (size_t)row * D_MODEL);
    o[t] = pa; o[t + 256] = pb;
}

// ---------------- RMSNorm (fp32 in) -> fp32 out -----------------------------
__global__ __launch_bounds__(256) void k_rmsnorm_f32(
        const float* __restrict__ x, const float* __restrict__ w,
        float* __restrict__ out) {
    int row = blockIdx.x, t = threadIdx.x;
    const float4* xr = (const float4*)(x + (size_t)row * D_MODEL);
    float4 a = xr[t], b = xr[t + 256];
    float ss = a.x*a.x + a.y*a.y + a.z*a.z + a.w*a.w
             + b.x*b.x + b.y*b.y + b.z*b.z + b.w*b.w;
    for (int m = 1; m < 64; m <<= 1) ss += __shfl_xor(ss, m);
    __shared__ float sred[4];
    if ((t & 63) == 0) sred[t >> 6] = ss;
    __syncthreads();
    float r = rsqrtf((sred[0] + sred[1] + sred[2] + sred[3]) * (1.0f / D_MODEL) + EPSV);
    const float4* wr = (const float4*)w;
    float4 wa = wr[t], wb = wr[t + 256];
    float4 oa, ob;
    oa.x = a.x * r * wa.x; oa.y = a.y * r * wa.y; oa.z = a.z * r * wa.z; oa.w = a.w * r * wa.w;
    ob.x = b.x * r * wb.x; ob.y = b.y * r * wb.y; ob.z = b.z * r * wb.z; ob.w = b.w * r * wb.w;
    float4* o = (float4*)(out + (size_t)row * D_MODEL);
    o[t] = oa; o[t + 256] = ob;
}

// -------- transpose + fp32->bf16: in [R][C] -> out [C][R] -------------------
__global__ __launch_bounds__(256) void k_transpose_cvt(
        const float* __restrict__ in, ushort_t* __restrict__ out, int R, int C) {
    __shared__ float tile[32][33];
    int bc = blockIdx.x * 32, br = blockIdx.y * 32;
    int t = threadIdx.x, lr = t >> 5, lc = t & 31;
    for (int i = 0; i < 4; i++)
        tile[lr + i * 8][lc] = in[(size_t)(br + lr + i * 8) * C + bc + lc];
    __syncthreads();
    for (int i = 0; i < 4; i++)
        out[(size_t)(bc + lr + i * 8) * R + br + lc] = f2b(tile[lc][lr + i * 8]);
}

// -------- GEMM v2 (m97 structure, BK=64): C = A[M,K](bf16)*Bt[N,K](bf16) ----
// R10-proven (-13us vs BK=32). XOR-swizzle via pre-swizzled global source.
template <int MODE>
__global__ __launch_bounds__(256) void k_gemm(
        const ushort_t* __restrict__ A, const ushort_t* __restrict__ Bt,
        void* __restrict__ Cout, const float* __restrict__ resid,
        int M, int N, int K) {
    __shared__ __align__(16) ushort_t sA[128 * 64];
    __shared__ __align__(16) ushort_t sB[128 * 64];
    int bm = blockIdx.y * 128, bn = blockIdx.x * 128;
    int t = threadIdx.x;
    int wv = t >> 6, lane = t & 63;
    int wm = (wv >> 1) * 64, wn = (wv & 1) * 64;
    int q4 = lane >> 4, n16 = lane & 15;

    int srow8 = lane >> 3;                     // 0..7
    int sxor  = ((lane & 7) ^ srow8) * 8;      // swizzled 16B-chunk offset
    const ushort_t* gA = A  + (size_t)(bm + wv * 32 + srow8) * K + sxor;
    const ushort_t* gB = Bt + (size_t)(bn + wv * 32 + srow8) * K + sxor;
    ushort_t* lA = sA + wv * 32 * 64;
    ushort_t* lB = sB + wv * 32 * 64;

    floatx4 zero4 = {0.0f, 0.0f, 0.0f, 0.0f};
    floatx4 acc[4][4];
    for (int i = 0; i < 4; i++)
        for (int j = 0; j < 4; j++) acc[i][j] = zero4;

    for (int k0 = 0; k0 < K; k0 += 64) {
        #pragma unroll
        for (int i = 0; i < 4; i++) {
            GLD_LDS16(gA + (size_t)(i * 8) * K + k0, lA + i * 8 * 64);
            GLD_LDS16(gB + (size_t)(i * 8) * K + k0, lB + i * 8 * 64);
        }
        __syncthreads();
        #pragma unroll
        for (int kk = 0; kk < 2; kk++) {
            short8 af[4], bfr[4];
            for (int i = 0; i < 4; i++) {
                int row = wm + i * 16 + n16;
                af[i]  = *(const short8*)&sA[row * 64 + (((kk * 4 + q4) ^ (row & 7)) * 8)];
            }
            for (int j = 0; j < 4; j++) {
                int row = wn + j * 16 + n16;
                bfr[j] = *(const short8*)&sB[row * 64 + (((kk * 4 + q4) ^ (row & 7)) * 8)];
            }
            for (int i = 0; i < 4; i++)
                for (int j = 0; j < 4; j++)
                    acc[i][j] = __builtin_amdgcn_mfma_f32_16x16x32_bf16(af[i], bfr[j], acc[i][j], 0, 0, 0);
        }
        __syncthreads();
    }

    for (int i = 0; i < 4; i++) {
        int rbase = bm + wm + i * 16 + q4 * 4;
        for (int j = 0; j < 4; j++) {
            int col = bn + wn + j * 16 + n16;
            if (MODE == 0) {
                ushort_t* C = (ushort_t*)Cout;
                for (int r = 0; r < 4; r++) {
                    float v = acc[i][j][r];
                    v = fminf(fmaxf(v, -8.0f), 8.0f);
                    C[(size_t)(rbase + r) * N + col] = f2b(v);
                }
            } else {
                float* C = (float*)Cout;
                for (int r = 0; r < 4; r++) {
                    float v = acc[i][j][r] + resid[(size_t)(rbase + r) * N + col];
                    C[(size_t)(rbase + r) * N + col] = v;
                }
            }
        }
    }
}

// -------- RoPE for K slots only (Q fused into attn prologue) ----------------
__global__ __launch_bounds__(256) void k_ropeK(
        const ushort_t* __restrict__ qkv, const int* __restrict__ pos_ids,
        const float* __restrict__ rsin, const float* __restrict__ rcos,
        ushort_t* __restrict__ kout) {
    int wid  = blockIdx.x * 4 + (threadIdx.x >> 6);   // [0, ROWS*4)
    int lane = threadIdx.x & 63;
    int row = wid >> 2, kslot = wid & 3;
    int b = row >> 11, s = row & 2047;
    int pos = pos_ids[row];
    int col0 = D_MODEL + kslot * HD;
    const ushort_t* src = qkv + (size_t)row * QKV_N + col0;
    float xl = b2f(src[lane]);
    float xh = b2f(src[lane + 64]);
    const float* cp = rcos + (size_t)pos * HD;
    const float* sp = rsin + (size_t)pos * HD;
    float cl = cp[lane], sl = sp[lane];
    float ch = cp[lane + 64], sh = sp[lane + 64];
    float ol = xl * cl - xh * sl;
    float oh = xh * ch + xl * sh;
    size_t dst = ((size_t)(b * NKV + kslot) * SEQ + s) * HD;
    kout[dst + lane] = f2b(ol); kout[dst + lane + 64] = f2b(oh);
}

// -------- V transpose: qkv v-slot -> vt [NB,NKV,HD,SEQ] ---------------------
__global__ __launch_bounds__(256) void k_vtrans(
        const ushort_t* __restrict__ qkv, ushort_t* __restrict__ vt) {
    __shared__ ushort_t tile[32][33];
    int bh = blockIdx.z;
    int b = bh >> 2, h = bh & 3;
    int s0 = blockIdx.x * 32, d0 = blockIdx.y * 32;
    int t = threadIdx.x, lr = t >> 5, lc = t & 31;
    int col0 = D_MODEL + NKV * HD + h * HD;
    for (int i = 0; i < 4; i++)
        tile[lr + i * 8][lc] =
            qkv[((size_t)b * SEQ + s0 + lr + i * 8) * QKV_N + col0 + d0 + lc];
    __syncthreads();
    for (int i = 0; i < 4; i++)
        vt[((size_t)bh * HD + d0 + lr + i * 8) * SEQ + s0 + lc] = tile[lc][lr + i * 8];
}

// -------- MFMA flash attention v5q: v5 loop + Q-RoPE fused in prologue ------
// Block: 4 waves x 16q = 64 q. Grid: 32 qt x 32 bh = 1024 blocks (LPT desc).
// K-loop byte-identical to R1-proven v5 (102.6us). Prologue change only:
// Q is read straight from qkv (clipped bf16) and RoPE'd in registers.
// v5 frag chunks pair exactly under rotate_half: chunk o pairs with o^64,
// i.e. qf[0]<->qf[2], qf[1]<->qf[3] (o = kk*32+q4*8; o^64 = (kk^2)*32+q4*8).
// Removes the qrot buffer + 32MB of HBM round-trip; numerics identical
// (b2f -> f32 rope -> f2b, same as old k_rope path).
__global__ __launch_bounds__(256, 2) void k_attn(
        const ushort_t* __restrict__ qkv, const int* __restrict__ pos_ids,
        const float* __restrict__ rsin, const float* __restrict__ rcos,
        const ushort_t* __restrict__ Kr, const ushort_t* __restrict__ Vt,
        const int* __restrict__ amask, ushort_t* __restrict__ O) {
    int bidx = blockIdx.x;
    int qt = (SEQ / 64 - 1) - (bidx >> 5);    // LPT: long blocks first
    int bh = bidx & 31, h = bh & 15, b = bh >> 4;
    int wave = threadIdx.x >> 6, lane = threadIdx.x & 63;
    int q4 = lane >> 4, n16 = lane & 15;

    __shared__ __align__(16) ushort_t sK[2][64 * 128];   // [kv][d], swizzled
    __shared__ __align__(16) ushort_t sV[2][128 * 64];   // [d][kv], swizzled

    const ushort_t* Kh = Kr + (size_t)(b * NKV + (h >> 2)) * SEQ * HD;
    const ushort_t* Vh = Vt + (size_t)(b * NKV + (h >> 2)) * HD * SEQ;
    const int* am = amask + b * SEQ;

    int q0 = qt * 64 + wave * 16;             // this wave's 16 q cols
    int qcol = q0 + n16;

    // ---- Q load + fused RoPE (register-level; QPRE folded) ----
    short8 qf[4];                              // Q as B-frag: d = kk*32+q4*8+j
    {
        const ushort_t* qsrc = qkv + (size_t)(b * SEQ + qcol) * QKV_N + h * HD;
        int pos = pos_ids[b * SEQ + qcol];
        const float* cp = rcos + (size_t)pos * HD;
        const float* sp = rsin + (size_t)pos * HD;
        #pragma unroll
        for (int kk = 0; kk < 2; kk++) {
            int o_lo = kk * 32 + q4 * 8;      // < 64
            int o_hi = o_lo + 64;
            short8 xl8 = *(const short8*)(qsrc + o_lo);
            short8 xh8 = *(const short8*)(qsrc + o_hi);
            union { ushort_t u[8]; short8 s; } alo, ahi;
            #pragma unroll
            for (int j = 0; j < 8; j++) {
                float xl = b2f((ushort_t)xl8[j]);
                float xh = b2f((ushort_t)xh8[j]);
                alo.u[j] = f2b((xl * cp[o_lo + j] - xh * sp[o_lo + j]) * QPRE);
                ahi.u[j] = f2b((xh * cp[o_hi + j] + xl * sp[o_hi + j]) * QPRE);
            }
            qf[kk] = alo.s;
            qf[kk + 2] = ahi.s;
        }
    }

    floatx4 zero4 = {0.0f, 0.0f, 0.0f, 0.0f};
    floatx4 o_acc[8];                          // O^T[d][q]: d = dt*16+q4*4+r, col q=n16
    for (int dt = 0; dt < 8; dt++) o_acc[dt] = zero4;
    float m_i = -INFINITY, l_i = 0.0f;

    // staging lane geometry (computed once)
    int krow_l = (lane >> 4);                  // + wave*16 + t*4
    int kc_l   = lane & 15;
    int vrow_l = (lane >> 3);                  // + wave*32 + t*8
    int vc_l   = lane & 7;

    auto stage_kv = [&](int buf, int kv0) {
        #pragma unroll
        for (int t = 0; t < 4; t++) {
            int krow = wave * 16 + t * 4 + krow_l;
            int kc   = kc_l ^ (krow & 7);
            GLD_LDS16(Kh + (size_t)(kv0 + krow) * HD + kc * 8,
                      &sK[buf][(wave * 16 + t * 4) * 128]);
            int vrow = wave * 32 + t * 8 + vrow_l;
            int vc   = vc_l ^ (vrow & 7);
            GLD_LDS16(Vh + (size_t)vrow * SEQ + kv0 + vc * 8,
                      &sV[buf][(wave * 32 + t * 8) * 64]);
        }
    };

    int kv_iters = qt + 1;

    // prologue: fill buffer 0, full drain
    stage_kv(0, 0);
    asm volatile("s_waitcnt vmcnt(0)" ::: "memory");
    __builtin_amdgcn_s_barrier();
    __builtin_amdgcn_sched_barrier(0);

    for (int it = 0; it < kv_iters; it++) {
        int cur = it & 1;
        int kv0 = it * 64;
        // issue next tile's loads FIRST -- they stay in flight across all of
        // this iteration's compute; drained only at the bottom vmcnt(0).
        if (it + 1 < kv_iters)
            stage_kv(cur ^ 1, kv0 + 64);

        const ushort_t* sKc = sK[cur];
        const ushort_t* sVc = sV[cur];

        bool tail = (kv0 + 63 > q0);           // wave-uniform causal-mask need
        // ---- S^T = K·Q^T: rows kv = q4*4+r (+jj*16), col q = n16 ----
        floatx4 st[4];
        for (int jj = 0; jj < 4; jj++) st[jj] = zero4;
        for (int jj = 0; jj < 4; jj++) {
            int krow = jj * 16 + n16;
            int sw = krow & 7;
            const ushort_t* kb = sKc + krow * 128;
            for (int kk = 0; kk < 4; kk++) {
                short8 kf = *(const short8*)(kb + ((kk * 4 + q4) ^ sw) * 8);
                st[jj] = __builtin_amdgcn_mfma_f32_16x16x32_bf16(kf, qf[kk], st[jj], 0, 0, 0);
            }
        }
        // ---- mask ----
        for (int jj = 0; jj < 4; jj++) {
            int kvb = kv0 + jj * 16 + q4 * 4;
            int4 am4 = *(const int4*)(am + kvb);
            int amr[4] = {am4.x, am4.y, am4.z, am4.w};
            if (tail) {
                for (int r = 0; r < 4; r++)
                    st[jj][r] = (amr[r] > 0 && kvb + r <= qcol) ? st[jj][r] : -1e30f;
            } else {
                for (int r = 0; r < 4; r++)
                    st[jj][r] = (amr[r] > 0) ? st[jj][r] : -1e30f;
            }
        }
        // ---- online softmax (kv in regs + q4 groups: 2 shuffles per reduce)
        //      T13 deferred rescale: keep old max unless grown by > 8
        //      (log2 domain -> P bounded by 2^8; bf16-safe, f32 accum) ----
        float mx = st[0][0];
        for (int jj = 0; jj < 4; jj++)
            for (int r = 0; r < 4; r++) mx = fmaxf(mx, st[jj][r]);
        mx = fmaxf(mx, __shfl_xor(mx, 16));
        mx = fmaxf(mx, __shfl_xor(mx, 32));
        if (!__all(mx - m_i <= 8.0f)) {
            float mnew = fmaxf(m_i, mx);
            float al = exp2f(m_i - mnew);
            m_i = mnew;
            l_i *= al;
            for (int dt = 0; dt < 8; dt++)
                o_acc[dt] *= al;
        }
        float rs = 0.0f;
        for (int jj = 0; jj < 4; jj++)
            for (int r = 0; r < 4; r++) {
                float p = exp2f(st[jj][r] - m_i);
                st[jj][r] = p;
                rs += p;
            }
        rs += __shfl_xor(rs, 16);
        rs += __shfl_xor(rs, 32);
        l_i += rs;
        // ---- PV: A = V^T frags from LDS (8B), B = P^T from st regs ----
        for (int jj = 0; jj < 4; jj++) {
            union { unsigned u[2]; short4v s; } uu;
            uu.u[0] = pkbf(st[jj][0], st[jj][1]);
            uu.u[1] = pkbf(st[jj][2], st[jj][3]);
            short4v pfr = uu.s;
            int ch = jj * 2 + (q4 >> 1), hh = q4 & 1;
            for (int dt = 0; dt < 8; dt++) {
                int vrow = dt * 16 + n16;
                short4v vf = *(const short4v*)(sVc + vrow * 64 + ((ch ^ (vrow & 7)) * 8) + hh * 4);
                o_acc[dt] = pv_mfma(vf, pfr, o_acc[dt]);
            }
        }
        // ---- single per-iter drain: own prefetch landed + all waves done
        //      reading buf[cur] (their ds_reads were consumed by MFMAs) ----
        asm volatile("s_waitcnt vmcnt(0)" ::: "memory");
        __builtin_amdgcn_s_barrier();
        __builtin_amdgcn_sched_barrier(0);
    }
    // ---- epilogue: O^T lane holds d = dt*16+q4*4+r for col q = n16 ----
    float inv = 1.0f / l_i;
    ushort_t* orow = O + ((size_t)(b * SEQ) + qcol) * D_MODEL + h * HD + q4 * 4;
    for (int dt = 0; dt < 8; dt++) {
        uint2 pk;
        pk.x = pkbf(o_acc[dt][0] * inv, o_acc[dt][1] * inv);
        pk.y = pkbf(o_acc[dt][2] * inv, o_acc[dt][3] * inv);
        *(uint2*)(orow + dt * 16) = pk;
    }
}

// ---------------------------------------------------------------------------
extern "C" void kernel_launch(void* const* d_in, const int* in_sizes, int n_in,
                              void* d_out, int out_size, void* d_ws, size_t ws_size,
                              hipStream_t stream) {
    const float* hidden = (const float*)d_in[0];
    const int*   amask  = (const int*)d_in[1];
    const int*   pos    = (const int*)d_in[2];
    const float* wqkv   = (const float*)d_in[3];
    const float* wout   = (const float*)d_in[4];
    const float* n1w    = (const float*)d_in[5];
    const float* n2w    = (const float*)d_in[6];
    const float* rsin   = (const float*)d_in[7];
    const float* rcos   = (const float*)d_in[8];
    float* out0 = (float*)d_out;
    float* out1 = out0 + (size_t)ROWS * D_MODEL;

    char* ws = (char*)d_ws;
    ushort_t* x_bf    = (ushort_t*)ws;  ws += (size_t)ROWS * D_MODEL * 2;
    ushort_t* wqkv_t  = (ushort_t*)ws;  ws += (size_t)QKV_N * D_MODEL * 2;
    ushort_t* wout_t  = (ushort_t*)ws;  ws += (size_t)D_MODEL * D_MODEL * 2;
    ushort_t* qkv     = (ushort_t*)ws;  ws += (size_t)ROWS * QKV_N * 2;
    ushort_t* krot    = (ushort_t*)ws;  ws += (size_t)NB * NKV * SEQ * HD * 2;
    ushort_t* vt      = (ushort_t*)ws;  ws += (size_t)NB * NKV * HD * SEQ * 2;
    ushort_t* attn    = (ushort_t*)ws;  ws += (size_t)ROWS * D_MODEL * 2;

    k_rmsnorm_bf16<<<ROWS, 256, 0, stream>>>(hidden, n1w, x_bf);
    k_transpose_cvt<<<dim3(QKV_N / 32, D_MODEL / 32), 256, 0, stream>>>(wqkv, wqkv_t, D_MODEL, QKV_N);
    k_transpose_cvt<<<dim3(D_MODEL / 32, D_MODEL / 32), 256, 0, stream>>>(wout, wout_t, D_MODEL, D_MODEL);
    k_gemm<0><<<dim3(QKV_N / 128, ROWS / 128), 256, 0, stream>>>(x_bf, wqkv_t, qkv, nullptr, ROWS, QKV_N, D_MODEL);
    k_ropeK<<<ROWS, 256, 0, stream>>>(qkv, pos, rsin, rcos, krot);
    k_vtrans<<<dim3(SEQ / 32, HD / 32, NB * NKV), 256, 0, stream>>>(qkv, vt);
    k_attn<<<(SEQ / 64) * 32, 256, 0, stream>>>(qkv, pos, rsin, rcos, krot, vt, amask, attn);
    k_gemm<1><<<dim3(D_MODEL / 128, ROWS / 128), 256, 0, stream>>>(attn, wout_t, out0, hidden, ROWS, D_MODEL, D_MODEL);
    k_rmsnorm_f32<<<ROWS, 256, 0, stream>>>(out0, n2w, out1);
}